// Round 12
// baseline (255.126 us; speedup 1.0000x reference)
//
#include <hip/hip_runtime.h>

#define BSZ 256
#define NND 22
#define BN_EPS 1e-5f

// ---------------------------------------------------------------------------
// conv core for CIN<=4 (used by S1 only). c-loop unroll-1 ON PURPOSE
// (R4-R7 lesson): full unroll at CIN>=4 blows VGPR to 164-256.
// ---------------------------------------------------------------------------
template<int CIN, int COUT, int R, int SROW>
__device__ __forceinline__ void conv_coreR(
    const float (*s_in)[SROW], const float* s_w, int tid, float y[COUT][R]) {
#pragma unroll
  for (int o = 0; o < COUT; o++)
#pragma unroll
    for (int r = 0; r < R; r++) y[o][r] = 0.f;
#pragma unroll 1
  for (int c = 0; c < CIN; c++) {
    float xr[R + 6];
    if constexpr (R == 4) {
      const float4* xp = (const float4*)&s_in[c][4 * tid];
      float4 xa = xp[0], xb = xp[1];
      float2 xc = *(const float2*)&s_in[c][4 * tid + 8];
      xr[0] = xa.x; xr[1] = xa.y; xr[2] = xa.z; xr[3] = xa.w;
      xr[4] = xb.x; xr[5] = xb.y; xr[6] = xb.z; xr[7] = xb.w;
      xr[8] = xc.x; xr[9] = xc.y;
    } else {
      const float2* xp = (const float2*)&s_in[c][2 * tid];
      float2 x0 = xp[0], x1 = xp[1], x2 = xp[2], x3 = xp[3];
      xr[0] = x0.x; xr[1] = x0.y; xr[2] = x1.x; xr[3] = x1.y;
      xr[4] = x2.x; xr[5] = x2.y; xr[6] = x3.x; xr[7] = x3.y;
    }
#pragma unroll
    for (int k = 0; k < 7; k++) {
      const float4* wp = (const float4*)&s_w[(c * 7 + k) * COUT];
#pragma unroll
      for (int o4 = 0; o4 < COUT / 4; o4++) {
        float4 wv = wp[o4];
#pragma unroll
        for (int r = 0; r < R; r++) {
          y[4 * o4 + 0][r] += wv.x * xr[r + k];
          y[4 * o4 + 1][r] += wv.y * xr[r + k];
          y[4 * o4 + 2][r] += wv.z * xr[r + k];
          y[4 * o4 + 3][r] += wv.w * xr[r + k];
        }
      }
    }
  }
}

template<int CIN, int COUT, int NTH>
__device__ __forceinline__ void stage_weights(const float* __restrict__ w,
                                              float* s_w, int tid) {
  for (int i = tid; i < CIN * 7 * COUT; i += NTH) {
    int c = i / (7 * COUT), k = (i / COUT) % 7, o = i % COUT;
    s_w[i] = w[(o * CIN + c) * 7 + k];
  }
}

// ---------------------------------------------------------------------------
// S1: stats of conv1 over x -> private partial slot. (unchanged, proven)
// ---------------------------------------------------------------------------
template<int CIN, int COUT, int LIN, int NTH, int NT, int R>
__global__ __launch_bounds__(NTH) void conv_statsR(
    const float* __restrict__ in, long sn, long sb, long sc,
    const float* __restrict__ w, float* __restrict__ part) {
  const int TILE = R * NTH;
  const int SROW = TILE + 8;
  __shared__ alignas(16) float s_in[CIN][SROW];
  __shared__ alignas(16) float s_w[CIN * 7 * COUT];
  __shared__ float s_red[2][NTH / 64][COUT];
  int tid = threadIdx.x, n = blockIdx.z, b = blockIdx.y;
  int t0 = blockIdx.x * TILE;
  const float* base = in + (long)n * sn + (long)b * sb;
  stage_weights<CIN, COUT, NTH>(w, s_w, tid);
  for (int c = 0; c < CIN; c++)
    for (int i = tid; i < TILE + 6; i += NTH) {
      int l = t0 + i - 3;
      s_in[c][i] = (l >= 0 && l < LIN) ? base[(long)c * sc + l] : 0.f;
    }
  __syncthreads();
  float y[COUT][R];
  conv_coreR<CIN, COUT, R, SROW>(s_in, s_w, tid, y);
  bool valid = (t0 + R * tid) < LIN;
  int lane = tid & 63, wv = tid >> 6;
#pragma unroll
  for (int o = 0; o < COUT; o++) {
    float s = 0.f, q = 0.f;
    if (valid) {
#pragma unroll
      for (int r = 0; r < R; r++) { s += y[o][r]; q += y[o][r] * y[o][r]; }
    }
#pragma unroll
    for (int off = 32; off > 0; off >>= 1) {
      s += __shfl_down(s, off, 64);
      q += __shfl_down(q, off, 64);
    }
    if (lane == 0) { s_red[0][wv][o] = s; s_red[1][wv][o] = q; }
  }
  __syncthreads();
  if (tid < COUT) {
    float s = 0.f, q = 0.f;
#pragma unroll
    for (int g = 0; g < NTH / 64; g++) { s += s_red[0][g][tid]; q += s_red[1][g][tid]; }
    long slot = ((long)n * NT + blockIdx.x) * BSZ + b;
    part[slot * (2 * COUT) + tid] = s;
    part[slot * (2 * COUT) + COUT + tid] = q;
  }
}

// ---------------------------------------------------------------------------
// Reduce partials -> BN scale/shift. scs[n*64+o]=scale, scs[n*64+32+o]=shift
// Optionally (w2t != nullptr, block 0) also pre-transposes conv2/conv3
// weights to [c][k][o] global buffers (folded prep_weights launch).
// ---------------------------------------------------------------------------
template<int C, int NSLOT, int LIN>
__global__ __launch_bounds__(256) void stats_reduce(
    const float* __restrict__ part,
    const float* __restrict__ gamma, const float* __restrict__ beta,
    float* __restrict__ scs,
    const float* __restrict__ w2, const float* __restrict__ w3,
    float* __restrict__ w2t, float* __restrict__ w3t) {
  const int V = 2 * C;
  const int GRP = 256 / V;
  int n = blockIdx.x, tid = threadIdx.x;
  int j = tid % V, g = tid / V;
  const float* p = part + (long)n * NSLOT * V;
  float s = 0.f;
  for (int sl = g; sl < NSLOT; sl += GRP) s += p[(long)sl * V + j];
  __shared__ float red[V][GRP];
  __shared__ float tot[V];
  red[j][g] = s;
  __syncthreads();
  if (tid < V) {
    float t = 0.f;
#pragma unroll
    for (int gg = 0; gg < GRP; gg++) t += red[tid][gg];
    tot[tid] = t;
  }
  __syncthreads();
  if (tid < C) {
    float cnt = (float)BSZ * (float)LIN;
    float m = tot[tid] / cnt;
    float var = tot[C + tid] / cnt - m * m;
    float istd = 1.0f / sqrtf(var + BN_EPS);
    float scl = gamma[tid] * istd;
    scs[n * 64 + tid] = scl;
    scs[n * 64 + 32 + tid] = beta[tid] - m * scl;
  }
  if (w2t != nullptr && blockIdx.x == 0) {
    if (tid < 224) {
      int c = tid / 56, k = (tid / 8) % 7, o = tid & 7;
      w2t[tid] = w2[(o * 4 + c) * 7 + k];
    }
    for (int i = tid; i < 896; i += 256) {
      int c = i / 112, k = (i / 16) % 7, o = i & 15;
      w3t[i] = w3[(o * 8 + c) * 7 + k];
    }
  }
}

// ---------------------------------------------------------------------------
// F1: conv1+BN1+ReLU+pool -> h1 (LDS ONLY) -> conv2 -> pooled raw conv2 to
// global (y2p; scale2>0 so maxpool∘relu∘BN == relu∘BN∘maxpool) + stats2
// partials. Phase-B x-reads are software-pipelined (double-buffered regs,
// guard-free via garbage row s_h1[4]) to hide LDS latency under FMAs.
// grid: (1, B, N), block 256.
// ---------------------------------------------------------------------------
__global__ __launch_bounds__(256) void fused1(
    const float* __restrict__ x,      // (B, N, 2000)
    const float* __restrict__ w1,     // (4,1,7)
    const float* __restrict__ scs1,
    const float* __restrict__ w2t,    // [c][k][o] transposed conv2 weights
    float* __restrict__ y2p,          // [n][b][8][500] pooled raw conv2
    float* __restrict__ p2) {         // [(n*256+b)*16]
  __shared__ alignas(16) float s_x[2016];       // s_x[j+4] = x[j]
  __shared__ alignas(16) float s_h1[5][1008];   // row 4 = garbage prefetch row
  __shared__ float s_sc[4], s_sh[4];
  __shared__ float s_red[2][4][8];
  int tid = threadIdx.x, n = blockIdx.z, b = blockIdx.y;
  const float* xb = x + (long)b * (NND * 2000) + (long)n * 2000;
  if (tid < 4) { s_sc[tid] = scs1[n * 64 + tid]; s_sh[tid] = scs1[n * 64 + 32 + tid]; }
  {  // batched staging: both global loads issued before any LDS write
    float4 a0 = *(const float4*)&xb[4 * tid];
    float4 a1;
    bool m1 = tid + 256 < 500;
    if (m1) a1 = *(const float4*)&xb[4 * (tid + 256)];
    *(float4*)&s_x[4 * tid + 4] = a0;
    if (m1) *(float4*)&s_x[4 * (tid + 256) + 4] = a1;
  }
  if (tid == 0) {
    *(float4*)&s_x[0] = make_float4(0.f, 0.f, 0.f, 0.f);
    *(float4*)&s_x[2004] = make_float4(0.f, 0.f, 0.f, 0.f);
  }
  __syncthreads();
  // ---- Phase A: conv1 (8 pos/thread) + BN1 + ReLU + pool -> s_h1 ----
  if (tid < 250) {                                  // 8*250 = 2000 exactly
    float xr[16];
    const float4* xp = (const float4*)&s_x[8 * tid];
#pragma unroll
    for (int v = 0; v < 4; v++) {
      float4 t = xp[v];
      xr[4 * v + 0] = t.x; xr[4 * v + 1] = t.y;
      xr[4 * v + 2] = t.z; xr[4 * v + 3] = t.w;
    }
    float y[4][8];
#pragma unroll
    for (int o = 0; o < 4; o++)
#pragma unroll
      for (int r = 0; r < 8; r++) y[o][r] = 0.f;
#pragma unroll
    for (int k = 0; k < 7; k++) {
      float w0 = w1[0 * 7 + k], w1v = w1[1 * 7 + k];
      float w2v = w1[2 * 7 + k], w3v = w1[3 * 7 + k];
#pragma unroll
      for (int r = 0; r < 8; r++) {
        y[0][r] += w0 * xr[r + k + 1];
        y[1][r] += w1v * xr[r + k + 1];
        y[2][r] += w2v * xr[r + k + 1];
        y[3][r] += w3v * xr[r + k + 1];
      }
    }
#pragma unroll
    for (int o = 0; o < 4; o++) {
      float a0 = y[o][0] * s_sc[o] + s_sh[o], a1 = y[o][1] * s_sc[o] + s_sh[o];
      float a2 = y[o][2] * s_sc[o] + s_sh[o], a3 = y[o][3] * s_sc[o] + s_sh[o];
      float a4 = y[o][4] * s_sc[o] + s_sh[o], a5 = y[o][5] * s_sc[o] + s_sh[o];
      float a6 = y[o][6] * s_sc[o] + s_sh[o], a7 = y[o][7] * s_sc[o] + s_sh[o];
      float4 v;
      v.x = fmaxf(fmaxf(a0, a1), 0.f);
      v.y = fmaxf(fmaxf(a2, a3), 0.f);
      v.z = fmaxf(fmaxf(a4, a5), 0.f);
      v.w = fmaxf(fmaxf(a6, a7), 0.f);
      *(float4*)&s_h1[o][4 * tid + 4] = v;      // 16B-aligned, conflict-free
    }
  }
  if (tid < 4) {
    *(float4*)&s_h1[tid][0] = make_float4(0.f, 0.f, 0.f, 0.f);
    *(float4*)&s_h1[tid][1004] = make_float4(0.f, 0.f, 0.f, 0.f);
  }
  __syncthreads();
  // ---- Phase B: conv2 (pipelined x-reads) -> stats2 + pooled raw y2p ----
  float y2[8][4];
#pragma unroll
  for (int o = 0; o < 8; o++)
#pragma unroll
    for (int r = 0; r < 4; r++) y2[o][r] = 0.f;
  if (tid < 250) {                                  // 4*250 = 1000 exactly
    const float4* xp0 = (const float4*)&s_h1[0][4 * tid];
    float4 n0 = xp0[0], n1 = xp0[1], n2 = xp0[2];
#pragma unroll 1
    for (int c = 0; c < 4; c++) {
      float4 c0 = n0, c1 = n1, c2 = n2;
      const float4* xpn = (const float4*)&s_h1[c + 1][4 * tid];  // row4 garbage ok
      n0 = xpn[0]; n1 = xpn[1]; n2 = xpn[2];
      float xr[12];
      xr[0] = c0.x; xr[1] = c0.y; xr[2] = c0.z; xr[3] = c0.w;
      xr[4] = c1.x; xr[5] = c1.y; xr[6] = c1.z; xr[7] = c1.w;
      xr[8] = c2.x; xr[9] = c2.y; xr[10] = c2.z; xr[11] = c2.w;
#pragma unroll
      for (int k = 0; k < 7; k++) {
        float4 w0 = *(const float4*)&w2t[(c * 7 + k) * 8];       // s_load
        float4 w1v = *(const float4*)&w2t[(c * 7 + k) * 8 + 4];
#pragma unroll
        for (int r = 0; r < 4; r++) {
          float xv = xr[r + k + 1];
          y2[0][r] += w0.x * xv;
          y2[1][r] += w0.y * xv;
          y2[2][r] += w0.z * xv;
          y2[3][r] += w0.w * xv;
          y2[4][r] += w1v.x * xv;
          y2[5][r] += w1v.y * xv;
          y2[6][r] += w1v.z * xv;
          y2[7][r] += w1v.w * xv;
        }
      }
    }
    long yb = ((long)n * BSZ + b) * 4000 + 2 * tid;
#pragma unroll
    for (int o = 0; o < 8; o++) {
      float2 v;
      v.x = fmaxf(y2[o][0], y2[o][1]);
      v.y = fmaxf(y2[o][2], y2[o][3]);
      *(float2*)&y2p[yb + o * 500] = v;
    }
  }
  int lane = tid & 63, wv = tid >> 6;
#pragma unroll
  for (int o = 0; o < 8; o++) {
    float s = y2[o][0] + y2[o][1] + y2[o][2] + y2[o][3];
    float q = y2[o][0] * y2[o][0] + y2[o][1] * y2[o][1] +
              y2[o][2] * y2[o][2] + y2[o][3] * y2[o][3];
#pragma unroll
    for (int off = 32; off > 0; off >>= 1) {
      s += __shfl_down(s, off, 64);
      q += __shfl_down(q, off, 64);
    }
    if (lane == 0) { s_red[0][wv][o] = s; s_red[1][wv][o] = q; }
  }
  __syncthreads();
  if (tid < 8) {
    float s = 0.f, q = 0.f;
#pragma unroll
    for (int g = 0; g < 4; g++) { s += s_red[0][g][tid]; q += s_red[1][g][tid]; }
    long slot = (long)n * BSZ + b;
    p2[slot * 16 + tid] = s;
    p2[slot * 16 + 8 + tid] = q;
  }
}

// ---------------------------------------------------------------------------
// F2: read y2p, BN2+ReLU -> h2 in LDS, conv3 (channel-split, pipelined
// x-reads via garbage row s_h2[8]) -> pooled raw conv3 (y3p) + stats3
// partials. grid: (1, B, N), block 256.
// ---------------------------------------------------------------------------
__global__ __launch_bounds__(256) void fused2(
    const float* __restrict__ y2p,    // [n][b][8][500]
    const float* __restrict__ scs2,
    const float* __restrict__ w3t,    // [c][k][o] transposed conv3 weights
    float* __restrict__ y3p,          // [n][b][16][250] pooled raw conv3
    float* __restrict__ p3) {         // [(n*256+b)*32]
  __shared__ alignas(16) float s_h2[9][512];    // row 8 = garbage prefetch row
  __shared__ float s_sc[8], s_sh[8];
  __shared__ float s_red[2][4][8];
  int tid = threadIdx.x, n = blockIdx.z, b = blockIdx.y;
  if (tid < 8) { s_sc[tid] = scs2[n * 64 + tid]; s_sh[tid] = scs2[n * 64 + 32 + tid]; }
  __syncthreads();
  // batched staging: 4 global loads issued together, then BN2+ReLU -> s_h2
  const float* yb2 = y2p + ((long)n * BSZ + b) * 4000;
  {
    int i0 = tid, i1 = tid + 256, i2 = tid + 512, i3 = tid + 768;
    int c0 = i0 / 125, j0 = i0 % 125;
    int c1 = i1 / 125, j1 = i1 % 125;
    int c2 = i2 / 125, j2 = i2 % 125;
    int c3 = i3 / 125, j3 = i3 % 125;
    bool m3 = i3 < 1000;
    float4 a0 = *(const float4*)&yb2[c0 * 500 + 4 * j0];
    float4 a1 = *(const float4*)&yb2[c1 * 500 + 4 * j1];
    float4 a2 = *(const float4*)&yb2[c2 * 500 + 4 * j2];
    float4 a3;
    if (m3) a3 = *(const float4*)&yb2[c3 * 500 + 4 * j3];
    float sc, sh;
    sc = s_sc[c0]; sh = s_sh[c0];
    a0.x = fmaxf(a0.x * sc + sh, 0.f); a0.y = fmaxf(a0.y * sc + sh, 0.f);
    a0.z = fmaxf(a0.z * sc + sh, 0.f); a0.w = fmaxf(a0.w * sc + sh, 0.f);
    *(float4*)&s_h2[c0][4 * j0 + 4] = a0;
    sc = s_sc[c1]; sh = s_sh[c1];
    a1.x = fmaxf(a1.x * sc + sh, 0.f); a1.y = fmaxf(a1.y * sc + sh, 0.f);
    a1.z = fmaxf(a1.z * sc + sh, 0.f); a1.w = fmaxf(a1.w * sc + sh, 0.f);
    *(float4*)&s_h2[c1][4 * j1 + 4] = a1;
    sc = s_sc[c2]; sh = s_sh[c2];
    a2.x = fmaxf(a2.x * sc + sh, 0.f); a2.y = fmaxf(a2.y * sc + sh, 0.f);
    a2.z = fmaxf(a2.z * sc + sh, 0.f); a2.w = fmaxf(a2.w * sc + sh, 0.f);
    *(float4*)&s_h2[c2][4 * j2 + 4] = a2;
    if (m3) {
      sc = s_sc[c3]; sh = s_sh[c3];
      a3.x = fmaxf(a3.x * sc + sh, 0.f); a3.y = fmaxf(a3.y * sc + sh, 0.f);
      a3.z = fmaxf(a3.z * sc + sh, 0.f); a3.w = fmaxf(a3.w * sc + sh, 0.f);
      *(float4*)&s_h2[c3][4 * j3 + 4] = a3;
    }
  }
  if (tid < 8) {
    *(float4*)&s_h2[tid][0] = make_float4(0.f, 0.f, 0.f, 0.f);
    *(float4*)&s_h2[tid][504] = make_float4(0.f, 0.f, 0.f, 0.f);
  }
  __syncthreads();
  // conv3 channel-split over in-LDS h2; pipelined x-reads; SGPR weights
  int og = __builtin_amdgcn_readfirstlane(tid >> 7);  // wave-uniform
  int pt = tid & 127;
  bool valid = pt < 125;                            // 4*125 = 500 exactly
  float y3[8][4];
#pragma unroll
  for (int o = 0; o < 8; o++)
#pragma unroll
    for (int r = 0; r < 4; r++) y3[o][r] = 0.f;
  if (valid) {
    const float4* xp0 = (const float4*)&s_h2[0][4 * pt];
    float4 n0 = xp0[0], n1 = xp0[1], n2 = xp0[2];
#pragma unroll 1
    for (int c = 0; c < 8; c++) {
      float4 c0 = n0, c1 = n1, c2 = n2;
      const float4* xpn = (const float4*)&s_h2[c + 1][4 * pt];  // row8 garbage ok
      n0 = xpn[0]; n1 = xpn[1]; n2 = xpn[2];
      float xr[12];
      xr[0] = c0.x; xr[1] = c0.y; xr[2] = c0.z; xr[3] = c0.w;
      xr[4] = c1.x; xr[5] = c1.y; xr[6] = c1.z; xr[7] = c1.w;
      xr[8] = c2.x; xr[9] = c2.y; xr[10] = c2.z; xr[11] = c2.w;
#pragma unroll
      for (int k = 0; k < 7; k++) {
        float4 w0 = *(const float4*)&w3t[(c * 7 + k) * 16 + og * 8];
        float4 w1v = *(const float4*)&w3t[(c * 7 + k) * 16 + og * 8 + 4];
#pragma unroll
        for (int r = 0; r < 4; r++) {
          float xv = xr[r + k + 1];
          y3[0][r] += w0.x * xv;
          y3[1][r] += w0.y * xv;
          y3[2][r] += w0.z * xv;
          y3[3][r] += w0.w * xv;
          y3[4][r] += w1v.x * xv;
          y3[5][r] += w1v.y * xv;
          y3[6][r] += w1v.z * xv;
          y3[7][r] += w1v.w * xv;
        }
      }
    }
    long yb = (((long)n * BSZ + b) * 16 + og * 8) * 250 + 2 * pt;
#pragma unroll
    for (int o = 0; o < 8; o++) {
      float2 v;
      v.x = fmaxf(y3[o][0], y3[o][1]);
      v.y = fmaxf(y3[o][2], y3[o][3]);
      *(float2*)&y3p[yb + o * 250] = v;
    }
  }
  int lane = tid & 63, wv = tid >> 6;
#pragma unroll
  for (int o = 0; o < 8; o++) {
    float s = y3[o][0] + y3[o][1] + y3[o][2] + y3[o][3];
    float q = y3[o][0] * y3[o][0] + y3[o][1] * y3[o][1] +
              y3[o][2] * y3[o][2] + y3[o][3] * y3[o][3];
#pragma unroll
    for (int off = 32; off > 0; off >>= 1) {
      s += __shfl_down(s, off, 64);
      q += __shfl_down(q, off, 64);
    }
    if (lane == 0) { s_red[0][wv][o] = s; s_red[1][wv][o] = q; }
  }
  __syncthreads();
  if (tid < 16) {
    int og2 = tid >> 3, o = tid & 7;
    float s = s_red[0][2 * og2][o] + s_red[0][2 * og2 + 1][o];
    float q = s_red[1][2 * og2][o] + s_red[1][2 * og2 + 1][o];
    long slot = (long)n * BSZ + b;
    p3[slot * 32 + tid] = s;
    p3[slot * 32 + 16 + tid] = q;
  }
}

// ---------------------------------------------------------------------------
// Graph tail WITH fused feat computation: phase 0 computes
// feat[n][ch] = mean(relu(BN3(y3p))) directly into LDS (same reduction
// order as the old feat_apply), then adjacency + 3 GCN layers + head.
// grid: (B), block: 256.
// ---------------------------------------------------------------------------
__global__ __launch_bounds__(256) void graph_head(
    const float* __restrict__ y3p,
    const float* __restrict__ scs3,
    const float* __restrict__ gw1, const float* __restrict__ gb1,
    const float* __restrict__ gw2, const float* __restrict__ gb2,
    const float* __restrict__ gw3, const float* __restrict__ gb3,
    const float* __restrict__ fw1, const float* __restrict__ fb1,
    const float* __restrict__ fw2, const float* __restrict__ fb2,
    float* __restrict__ out) {
  int b = blockIdx.x, tid = threadIdx.x;
  __shared__ float s_feat[NND][16];
  __shared__ float s_sq[NND];
  __shared__ float s_dist[NND][NND];
  __shared__ float s_adj[NND][NND];
  __shared__ float s_x[NND][128];
  __shared__ float s_t[NND][128];
  __shared__ float s_pool[128];
  __shared__ float s_h[64];
  // ---- Phase 0: feat (16 threads per (n,ch); group g handles ch=g) ----
  {
    int g = tid >> 4, s = tid & 15;
    for (int nn = 0; nn < NND; nn++) {
      const float* yb = y3p + (((long)nn * BSZ + b) * 16 + g) * 250;
      float sc = scs3[nn * 64 + g], sh = scs3[nn * 64 + 32 + g];
      float acc = 0.f;
      for (int j = s; j < 125; j += 16) {
        float2 v = *(const float2*)&yb[2 * j];
        acc += fmaxf(v.x * sc + sh, 0.f) + fmaxf(v.y * sc + sh, 0.f);
      }
#pragma unroll
      for (int off = 8; off > 0; off >>= 1) acc += __shfl_down(acc, off, 16);
      if (s == 0) s_feat[nn][g] = acc * (1.0f / 250.f);
    }
  }
  __syncthreads();
  if (tid < NND) {
    float s = 0.f;
    for (int c = 0; c < 16; c++) s += s_feat[tid][c] * s_feat[tid][c];
    s_sq[tid] = s;
  }
  __syncthreads();
  for (int i = tid; i < NND * NND; i += 256) {
    int nn = i / NND, m = i % NND;
    float d = 0.f;
    for (int c = 0; c < 16; c++) d += s_feat[nn][c] * s_feat[m][c];
    s_dist[nn][m] = s_sq[nn] + s_sq[m] - 2.f * d;  // diagonal exactly 0
    s_adj[nn][m] = 0.f;
  }
  __syncthreads();
  if (tid < NND) {  // top-4 smallest, ties -> earliest index (matches top_k)
    unsigned used = 0;
    for (int j = 0; j < 4; j++) {
      float best = 3.4e38f; int bi = 0;
      for (int m = 0; m < NND; m++)
        if (!((used >> m) & 1u) && s_dist[tid][m] < best) { best = s_dist[tid][m]; bi = m; }
      used |= 1u << bi;
      s_adj[tid][bi] = 0.25f;
    }
  }
  __syncthreads();
  for (int i = tid; i < NND * 32; i += 256) {
    int nn = i / 32, f = i % 32;
    float a = 0.f;
    for (int c = 0; c < 16; c++) a += s_feat[nn][c] * gw1[c * 32 + f];
    s_t[nn][f] = a;
  }
  __syncthreads();
  for (int i = tid; i < NND * 32; i += 256) {
    int nn = i / 32, f = i % 32;
    float a = gb1[f];
    for (int m = 0; m < NND; m++) a += s_adj[nn][m] * s_t[m][f];
    s_x[nn][f] = fmaxf(a, 0.f);
  }
  __syncthreads();
  for (int i = tid; i < NND * 64; i += 256) {
    int nn = i / 64, f = i % 64;
    float a = 0.f;
    for (int c = 0; c < 32; c++) a += s_x[nn][c] * gw2[c * 64 + f];
    s_t[nn][f] = a;
  }
  __syncthreads();
  for (int i = tid; i < NND * 64; i += 256) {
    int nn = i / 64, f = i % 64;
    float a = gb2[f];
    for (int m = 0; m < NND; m++) a += s_adj[nn][m] * s_t[m][f];
    s_x[nn][f] = fmaxf(a, 0.f);
  }
  __syncthreads();
  for (int i = tid; i < NND * 128; i += 256) {
    int nn = i / 128, f = i % 128;
    float a = 0.f;
    for (int c = 0; c < 64; c++) a += s_x[nn][c] * gw3[c * 128 + f];
    s_t[nn][f] = a;
  }
  __syncthreads();
  for (int i = tid; i < NND * 128; i += 256) {
    int nn = i / 128, f = i % 128;
    float a = gb3[f];
    for (int m = 0; m < NND; m++) a += s_adj[nn][m] * s_t[m][f];
    s_x[nn][f] = fmaxf(a, 0.f);
  }
  __syncthreads();
  if (tid < 128) {
    float a = 0.f;
    for (int m = 0; m < NND; m++) a += s_x[m][tid];
    s_pool[tid] = a * (1.0f / (float)NND);
  }
  __syncthreads();
  if (tid < 64) {
    float a = fb1[tid];
    for (int c = 0; c < 128; c++) a += s_pool[c] * fw1[c * 64 + tid];
    s_h[tid] = a;
  }
  __syncthreads();
  if (tid < 4) {
    float a = fb2[tid];
    for (int c = 0; c < 64; c++) a += s_h[c] * fw2[c * 4 + tid];
    out[b * 4 + tid] = a;
  }
}

extern "C" void kernel_launch(void* const* d_in, const int* in_sizes, int n_in,
                              void* d_out, int out_size, void* d_ws, size_t ws_size,
                              hipStream_t stream) {
  (void)in_sizes; (void)n_in; (void)out_size; (void)ws_size;
  const float* x   = (const float*)d_in[0];
  const float* w1  = (const float*)d_in[1];
  const float* g1  = (const float*)d_in[2];
  const float* b1  = (const float*)d_in[3];
  const float* w2  = (const float*)d_in[4];
  const float* g2  = (const float*)d_in[5];
  const float* b2  = (const float*)d_in[6];
  const float* w3  = (const float*)d_in[7];
  const float* g3  = (const float*)d_in[8];
  const float* b3  = (const float*)d_in[9];
  const float* gw1 = (const float*)d_in[10];
  const float* gb1 = (const float*)d_in[11];
  const float* gw2 = (const float*)d_in[12];
  const float* gb2 = (const float*)d_in[13];
  const float* gw3 = (const float*)d_in[14];
  const float* gb3 = (const float*)d_in[15];
  const float* fw1 = (const float*)d_in[16];
  const float* fb1 = (const float*)d_in[17];
  const float* fw2 = (const float*)d_in[18];
  const float* fb2 = (const float*)d_in[19];

  float* ws = (float*)d_ws;
  const long Y2 = (long)NND * BSZ * 8 * 500;    // 22,528,000 floats
  const long Y3 = (long)NND * BSZ * 16 * 250;   // 22,528,000 floats
  float* y2p  = ws;
  float* y3p  = y2p + Y2;
  float* scs1 = y3p + Y3;
  float* scs2 = scs1 + NND * 64;
  float* scs3 = scs2 + NND * 64;
  float* p1   = scs3 + NND * 64;                // 22*512 slots * 8
  float* p2   = p1 + (long)NND * 512 * 8;       // 22*256 slots * 16
  float* p3   = p2 + (long)NND * 256 * 16;      // 22*256 slots * 32
  float* w2t  = p3 + (long)NND * 256 * 32;      // 224
  float* w3t  = w2t + 224;                      // 896
  // total ws ~= 181 MB (same budget as prior passing rounds)

  // stats1 over x
  conv_statsR<1, 4, 2000, 256, 2, 4><<<dim3(2, BSZ, NND), dim3(256), 0, stream>>>(
      x, 2000, (long)NND * 2000, 0, w1, p1);
  // reduce1 (+ weight pre-transpose in block 0)
  stats_reduce<4, 512, 2000><<<dim3(NND), dim3(256), 0, stream>>>(
      p1, g1, b1, scs1, w2, w3, w2t, w3t);
  // conv1-apply + conv2 (pooled raw out) + stats2 (fused; h1 stays in LDS)
  fused1<<<dim3(1, BSZ, NND), dim3(256), 0, stream>>>(x, w1, scs1, w2t, y2p, p2);
  stats_reduce<8, 256, 1000><<<dim3(NND), dim3(256), 0, stream>>>(
      p2, g2, b2, scs2, nullptr, nullptr, nullptr, nullptr);
  // BN2-apply + conv3 (pooled raw out) + stats3 (fused; no conv2 recompute)
  fused2<<<dim3(1, BSZ, NND), dim3(256), 0, stream>>>(y2p, scs2, w3t, y3p, p3);
  stats_reduce<16, 256, 500><<<dim3(NND), dim3(256), 0, stream>>>(
      p3, g3, b3, scs3, nullptr, nullptr, nullptr, nullptr);
  // graph tail (absorbs feat_apply)
  graph_head<<<dim3(BSZ), dim3(256), 0, stream>>>(
      y3p, scs3, gw1, gb1, gw2, gb2, gw3, gb3, fw1, fb1, fw2, fb2, (float*)d_out);
}